// Round 1
// baseline (155.532 us; speedup 1.0000x reference)
//
#include <hip/hip_runtime.h>
#include <math.h>

#define EPSf 1e-12f

__device__ __forceinline__ void mm4(float* C, const float* X, const float* Y) {
#pragma unroll
  for (int i = 0; i < 4; ++i) {
#pragma unroll
    for (int j = 0; j < 4; ++j) {
      float acc = X[i*4+0] * Y[0*4+j];
      acc = fmaf(X[i*4+1], Y[1*4+j], acc);
      acc = fmaf(X[i*4+2], Y[2*4+j], acc);
      acc = fmaf(X[i*4+3], Y[3*4+j], acc);
      C[i*4+j] = acc;
    }
  }
}

// P = expm(Q*t) via JAX f32 algorithm (scale to L1<=3.9257, Pade-7, square).
// lfel[a]  = logsumexp_b( log(clip(P[a][b],1e-30)) + lfc[b] )
// dlfel[a] = d lfel[a] / dt   using dP/dt = Q @ P (exact for expm)
__device__ __forceinline__ void site_branch(const float* Qm, float t, const float* lfc,
                                            float* lfel, float* dlfel) {
  float M[16];
#pragma unroll
  for (int i = 0; i < 16; ++i) M[i] = Qm[i] * t;
  // induced 1-norm = max abs column sum
  float L1 = 0.f;
#pragma unroll
  for (int j = 0; j < 4; ++j) {
    float cs = fabsf(M[j]) + fabsf(M[4+j]) + fabsf(M[8+j]) + fabsf(M[12+j]);
    L1 = fmaxf(L1, cs);
  }
  const float maxnorm = 3.925724783138660f;
  int n = 0;
  if (L1 > maxnorm) {
    n = (int)ceilf(log2f(L1 / maxnorm));
    if (n < 0) n = 0;
  }
  const float sc = ldexpf(1.f, -n);
  float A_[16];
#pragma unroll
  for (int i = 0; i < 16; ++i) A_[i] = M[i] * sc;

  float A2[16], A4[16], A6[16];
  mm4(A2, A_, A_);
  mm4(A4, A2, A2);
  mm4(A6, A4, A2);

  // Pade-7: U = A(A6 + 1512*A4 + 277200*A2 + 8648640*I)
  //         V = 56*A6 + 25200*A4 + 1995840*A2 + 17297280*I
  float W[16], Vm[16];
#pragma unroll
  for (int i = 0; i < 16; ++i) {
    float w = fmaf(1512.f, A4[i], A6[i]);
    W[i] = fmaf(277200.f, A2[i], w);
    float vv = fmaf(25200.f, A4[i], 56.f * A6[i]);
    Vm[i] = fmaf(1995840.f, A2[i], vv);
  }
#pragma unroll
  for (int d = 0; d < 4; ++d) { W[d*5] += 8648640.f; Vm[d*5] += 17297280.f; }
  float U[16];
  mm4(U, A_, W);

  // Solve (V - U) R = (V + U): Gauss-Jordan, partial pivoting via static selects
  float Nm[16], Bm[16];
#pragma unroll
  for (int i = 0; i < 16; ++i) { Nm[i] = Vm[i] - U[i]; Bm[i] = Vm[i] + U[i]; }
#pragma unroll
  for (int c = 0; c < 4; ++c) {
#pragma unroll
    for (int r = 0; r < 4; ++r) {
      if (r > c) {
        bool sw = fabsf(Nm[r*4+c]) > fabsf(Nm[c*4+c]);
#pragma unroll
        for (int j = 0; j < 4; ++j) {
          float tn = Nm[c*4+j], tb = Bm[c*4+j];
          Nm[c*4+j] = sw ? Nm[r*4+j] : tn;
          Nm[r*4+j] = sw ? tn        : Nm[r*4+j];
          Bm[c*4+j] = sw ? Bm[r*4+j] : tb;
          Bm[r*4+j] = sw ? tb        : Bm[r*4+j];
        }
      }
    }
    float inv = 1.f / Nm[c*4+c];
#pragma unroll
    for (int j = 0; j < 4; ++j) { Nm[c*4+j] *= inv; Bm[c*4+j] *= inv; }
#pragma unroll
    for (int r = 0; r < 4; ++r) {
      if (r != c) {
        float f = Nm[r*4+c];
#pragma unroll
        for (int j = 0; j < 4; ++j) {
          Nm[r*4+j] = fmaf(-f, Nm[c*4+j], Nm[r*4+j]);
          Bm[r*4+j] = fmaf(-f, Bm[c*4+j], Bm[r*4+j]);
        }
      }
    }
  }
  float R[16];
#pragma unroll
  for (int i = 0; i < 16; ++i) R[i] = Bm[i];
  for (int k = 0; k < n; ++k) {
    float T[16];
    mm4(T, R, R);
#pragma unroll
    for (int i = 0; i < 16; ++i) R[i] = T[i];
  }
  // dP/dt = Q @ P
  float QP[16];
  mm4(QP, Qm, R);

#pragma unroll
  for (int a = 0; a < 4; ++a) {
    float x[4], dx[4];
#pragma unroll
    for (int b = 0; b < 4; ++b) {
      float pv = R[a*4+b];
      float pc = fmaxf(pv, 1e-30f);
      x[b] = logf(pc) + lfc[b];
      dx[b] = (pv > 1e-30f) ? (QP[a*4+b] / pv) : 0.f;  // clip grad is 0 below 1e-30
    }
    float m = fmaxf(fmaxf(x[0], x[1]), fmaxf(x[2], x[3]));
    float e0 = expf(x[0]-m), e1 = expf(x[1]-m), e2 = expf(x[2]-m), e3 = expf(x[3]-m);
    float S = e0+e1+e2+e3;
    lfel[a]  = m + logf(S);
    dlfel[a] = (e0*dx[0] + e1*dx[1] + e2*dx[2] + e3*dx[3]) / S;
  }
}

// block = one v (1024 blocks), thread = one site s (256 threads).
// All 3 gradient steps run inside the block; thread 0 writes final parents.
__global__ __launch_bounds__(256) void mlme_kernel(
    const float* __restrict__ c1g, const float* __restrict__ c2g,
    const float* __restrict__ lf1g, const float* __restrict__ lf2g,
    const float* __restrict__ spg,
    const float* __restrict__ W1g, const float* __restrict__ b1g,
    const float* __restrict__ Wqg, const float* __restrict__ bqg,
    const float* __restrict__ Wpg, const float* __restrict__ bpg,
    float* __restrict__ outg)
{
  __shared__ float sred[8];
  __shared__ float sAB[2];   // alpha, beta
  __shared__ float sPQ[8];   // p0,p1,q0,q1,c10,c11,c20,c21

  const int v = blockIdx.x;
  const int tid = threadIdx.x;
  const int lane = tid & 63;
  const int wid = tid >> 6;

  if (tid == 0) {
    float c10 = c1g[2*v], c11 = c1g[2*v+1];
    float c20 = c2g[2*v], c21 = c2g[2*v+1];
    float pn = sqrtf(c10*c10 + c11*c11 + EPSf);
    float qn = sqrtf(c20*c20 + c21*c21 + EPSf);
    float p0 = c10, p1 = c11, q0 = c20, q1 = c21;
    if (pn > qn) { float r = qn/pn; p0 = c10*r; p1 = c11*r; }
    if (qn > pn) { float r = pn/qn; q0 = c20*r; q1 = c21*r; }
    sPQ[0]=p0; sPQ[1]=p1; sPQ[2]=q0; sPQ[3]=q1;
    sPQ[4]=c10; sPQ[5]=c11; sPQ[6]=c20; sPQ[7]=c21;
    sAB[0]=0.5f; sAB[1]=0.5f;
  }

  // per-thread constants across all iterations
  float sprow[16];
#pragma unroll
  for (int k = 0; k < 4; ++k) {
    float4 t4 = reinterpret_cast<const float4*>(spg)[tid*4 + k];
    sprow[4*k+0]=t4.x; sprow[4*k+1]=t4.y; sprow[4*k+2]=t4.z; sprow[4*k+3]=t4.w;
  }
  float lfc1[4], lfc2[4];
  {
    float4 a = reinterpret_cast<const float4*>(lf1g)[v*256 + tid];
    float4 b = reinterpret_cast<const float4*>(lf2g)[v*256 + tid];
    lfc1[0]=a.x; lfc1[1]=a.y; lfc1[2]=a.z; lfc1[3]=a.w;
    lfc2[0]=b.x; lfc2[1]=b.y; lfc2[2]=b.z; lfc2[3]=b.w;
  }
  __syncthreads();

  for (int it = 0; it < 3; ++it) {
    const float alpha = sAB[0], beta = sAB[1];
    const float p0=sPQ[0], p1=sPQ[1], q0=sPQ[2], q1=sPQ[3];
    const float c10=sPQ[4], c11=sPQ[5], c20=sPQ[6], c21=sPQ[7];
    const float mid0 = p0*alpha + q0*(1.f-alpha);
    const float mid1 = p1*alpha + q1*(1.f-alpha);
    const float par0 = mid0*beta, par1 = mid1*beta;
    const float d10 = c10-par0, d11 = c11-par1;
    const float d20 = c20-par0, d21 = c21-par1;
    const float t1 = sqrtf(d10*d10 + d11*d11 + EPSf);
    const float t2 = sqrtf(d20*d20 + d21*d21 + EPSf);

    // MLP: h_j = relu(b1[j] + par.W1[0:2,j] + sprow.W1[2:18,j]); accumulate into
    // qraw = h@Wq + bq, praw = h@Wp + bp. Weight reads are wave-uniform -> s_load.
    float qraw[16], praw[4];
#pragma unroll
    for (int k = 0; k < 16; ++k) qraw[k] = bqg[k];
#pragma unroll
    for (int k = 0; k < 4; ++k) praw[k] = bpg[k];
#pragma unroll 4
    for (int j = 0; j < 64; ++j) {
      float acc = b1g[j];
      acc = fmaf(par0, W1g[j], acc);
      acc = fmaf(par1, W1g[64+j], acc);
#pragma unroll
      for (int k = 0; k < 16; ++k) acc = fmaf(sprow[k], W1g[(2+k)*64 + j], acc);
      float h = fmaxf(acc, 0.f);
#pragma unroll
      for (int k = 0; k < 16; ++k) qraw[k] = fmaf(h, Wqg[j*16+k], qraw[k]);
#pragma unroll
      for (int k = 0; k < 4; ++k) praw[k] = fmaf(h, Wpg[j*4+k], praw[k]);
    }

    // rate matrix: off-diag = softplus(qraw), diag = -rowsum(off-diag)
    float Qm[16];
#pragma unroll
    for (int a = 0; a < 4; ++a) {
      float rs = 0.f;
#pragma unroll
      for (int b = 0; b < 4; ++b) {
        if (b != a) {
          float xx = qraw[a*4+b];
          float r = fmaxf(xx, 0.f) + log1pf(expf(-fabsf(xx)));  // stable softplus
          Qm[a*4+b] = r;
          rs += r;
        }
      }
      Qm[a*4+a] = -rs;
    }

    // log stationary probs = log_softmax(praw)
    float lst[4];
    {
      float m = fmaxf(fmaxf(praw[0],praw[1]), fmaxf(praw[2],praw[3]));
      float e0=expf(praw[0]-m), e1=expf(praw[1]-m), e2=expf(praw[2]-m), e3=expf(praw[3]-m);
      float lS = logf(e0+e1+e2+e3);
      lst[0]=praw[0]-m-lS; lst[1]=praw[1]-m-lS; lst[2]=praw[2]-m-lS; lst[3]=praw[3]-m-lS;
    }

    float lfe1[4], dlf1[4], lfe2[4], dlf2[4];
    site_branch(Qm, t1, lfc1, lfe1, dlf1);
    site_branch(Qm, t2, lfc2, lfe2, dlf2);

    // ll = logsumexp_a(lfe1+lfe2+lst); dll/dt_k = sum_a softmax_a * dlfel_k[a]
    float z0 = lfe1[0]+lfe2[0]+lst[0];
    float z1 = lfe1[1]+lfe2[1]+lst[1];
    float z2 = lfe1[2]+lfe2[2]+lst[2];
    float z3 = lfe1[3]+lfe2[3]+lst[3];
    float mz = fmaxf(fmaxf(z0,z1), fmaxf(z2,z3));
    float w0=expf(z0-mz), w1=expf(z1-mz), w2=expf(z2-mz), w3=expf(z3-mz);
    float Sw = w0+w1+w2+w3;
    float g1c = (w0*dlf1[0]+w1*dlf1[1]+w2*dlf1[2]+w3*dlf1[3]) / Sw;
    float g2c = (w0*dlf2[0]+w1*dlf2[1]+w2*dlf2[2]+w3*dlf2[3]) / Sw;

    // block reduction over the 256 sites (deterministic butterfly + 4-wave sum)
#pragma unroll
    for (int off = 32; off > 0; off >>= 1) {
      g1c += __shfl_xor(g1c, off, 64);
      g2c += __shfl_xor(g2c, off, 64);
    }
    if (lane == 0) { sred[wid*2+0] = g1c; sred[wid*2+1] = g2c; }
    __syncthreads();
    if (tid == 0) {
      float g1 = sred[0]+sred[2]+sred[4]+sred[6];
      float g2 = sred[1]+sred[3]+sred[5]+sred[7];
      // chain rule through branch lengths only (Q, stat are stop_gradient'ed)
      float db1da = ((par0-c10)*(p0-q0) + (par1-c11)*(p1-q1)) * beta / t1;
      float db2da = ((par0-c20)*(p0-q0) + (par1-c21)*(p1-q1)) * beta / t2;
      float db1db = ((par0-c10)*mid0 + (par1-c11)*mid1) / t1;
      float db2db = ((par0-c20)*mid0 + (par1-c21)*mid1) / t2;
      float ga = g1*db1da + g2*db2da;
      float gb = g1*db1db + g2*db2db;
      ga = fminf(1.f, fmaxf(-1.f, ga));
      gb = fminf(1.f, fmaxf(-1.f, gb));
      sAB[0] = fminf(1.f, fmaxf(0.f, alpha + 0.1f*ga));
      sAB[1] = fminf(1.f, fmaxf(0.f, beta  + 0.1f*gb));
    }
    __syncthreads();
  }

  // 4th scan step only materializes parents with the final alpha/beta
  if (tid == 0) {
    const float alpha = sAB[0], beta = sAB[1];
    const float p0=sPQ[0], p1=sPQ[1], q0=sPQ[2], q1=sPQ[3];
    float mid0 = p0*alpha + q0*(1.f-alpha);
    float mid1 = p1*alpha + q1*(1.f-alpha);
    outg[2*v]   = mid0*beta;
    outg[2*v+1] = mid1*beta;
  }
}

extern "C" void kernel_launch(void* const* d_in, const int* in_sizes, int n_in,
                              void* d_out, int out_size, void* d_ws, size_t ws_size,
                              hipStream_t stream) {
  (void)in_sizes; (void)n_in; (void)d_ws; (void)ws_size; (void)out_size;
  const float* c1  = (const float*)d_in[0];
  const float* c2  = (const float*)d_in[1];
  const float* lf1 = (const float*)d_in[2];
  const float* lf2 = (const float*)d_in[3];
  const float* sp  = (const float*)d_in[4];
  const float* W1  = (const float*)d_in[5];
  const float* b1  = (const float*)d_in[6];
  const float* Wq  = (const float*)d_in[7];
  const float* bq  = (const float*)d_in[8];
  const float* Wp  = (const float*)d_in[9];
  const float* bp  = (const float*)d_in[10];
  float* out = (float*)d_out;

  mlme_kernel<<<dim3(1024), dim3(256), 0, stream>>>(
      c1, c2, lf1, lf2, sp, W1, b1, Wq, bq, Wp, bp, out);
}

// Round 2
// 71.116 us; speedup vs baseline: 2.1870x; 2.1870x over previous
//
#include <hip/hip_runtime.h>
#include <math.h>

#define EPSf 1e-12f

typedef float v2f __attribute__((ext_vector_type(2)));

__device__ __forceinline__ v2f v2fma(v2f a, v2f b, v2f c) {
  return __builtin_elementwise_fma(a, b, c);
}
__device__ __forceinline__ v2f mkv2(float a, float b) { v2f r; r.x = a; r.y = b; return r; }

// C = X * Y, 4x4 row-major stored as v2f[8] (row i = [2i]=cols01, [2i+1]=cols23)
__device__ __forceinline__ void mm4v(v2f* C, const v2f* X, const v2f* Y) {
#pragma unroll
  for (int i = 0; i < 4; ++i) {
    float x0 = X[2*i].x, x1 = X[2*i].y, x2 = X[2*i+1].x, x3 = X[2*i+1].y;
#pragma unroll
    for (int jp = 0; jp < 2; ++jp) {
      v2f acc = mkv2(x0, x0) * Y[0 + jp];
      acc = v2fma(mkv2(x1, x1), Y[2 + jp], acc);
      acc = v2fma(mkv2(x2, x2), Y[4 + jp], acc);
      acc = v2fma(mkv2(x3, x3), Y[6 + jp], acc);
      C[2*i + jp] = acc;
    }
  }
}

// One branch: given Q (and its shared powers), branch length t, f = exp(log_fels):
//   y  = clip(expm(Q t), 1e-30) @ f        (4-vector)
//   dy = Q @ y                              (d/dt of P@f, exact since dP/dt = Q P)
__device__ __forceinline__ void site_branch(const v2f* Qm, const v2f* Q2, const v2f* Q4,
                                            const v2f* Q6, float L1Q, float t,
                                            const float* f, float* y, float* dy) {
  // n_squarings = max(0, ceil(log2(L1/maxnorm))) via exponent bits
  float r = L1Q * t * 0.25472992f;  // 1/3.925724783138660
  int n = 0;
  if (r > 1.0f) {
    unsigned u = __float_as_uint(r);
    n = (int)(u >> 23) - 127 + (((u & 0x7fffffu) != 0u) ? 1 : 0);
  }
  float tau = t * __uint_as_float((unsigned)(127 - n) << 23);
  float t2 = tau * tau, t4 = t2 * t2, t6 = t4 * t2;

  // Pade-7 on A = Q*tau using shared powers: A2 = Q2*t2 etc.
  // W = A6 + 1512 A4 + 277200 A2 + 8648640 I ; V = 56 A6 + 25200 A4 + 1995840 A2 + 17297280 I
  const float cW6 = t6,        cW4 = 1512.f * t4,  cW2 = 277200.f * t2;
  const float cV6 = 56.f * t6, cV4 = 25200.f * t4, cV2 = 1995840.f * t2;
  v2f W[8], V[8];
#pragma unroll
  for (int ip = 0; ip < 8; ++ip) {
    W[ip] = v2fma(mkv2(cW6, cW6), Q6[ip], v2fma(mkv2(cW4, cW4), Q4[ip], mkv2(cW2, cW2) * Q2[ip]));
    V[ip] = v2fma(mkv2(cV6, cV6), Q6[ip], v2fma(mkv2(cV4, cV4), Q4[ip], mkv2(cV2, cV2) * Q2[ip]));
  }
  W[0].x += 8648640.f;  W[2].y += 8648640.f;  W[5].x += 8648640.f;  W[7].y += 8648640.f;
  V[0].x += 17297280.f; V[2].y += 17297280.f; V[5].x += 17297280.f; V[7].y += 17297280.f;

  v2f As[8], U[8];
#pragma unroll
  for (int ip = 0; ip < 8; ++ip) As[ip] = mkv2(tau, tau) * Qm[ip];
  mm4v(U, As, W);

  // Solve (V-U) R = (V+U), Gauss-Jordan with select-based partial pivoting
  float Nf[16], Bf[16];
#pragma unroll
  for (int ip = 0; ip < 8; ++ip) {
    v2f nn = V[ip] - U[ip], bb = V[ip] + U[ip];
    Nf[2*ip] = nn.x; Nf[2*ip+1] = nn.y;
    Bf[2*ip] = bb.x; Bf[2*ip+1] = bb.y;
  }
#pragma unroll
  for (int c = 0; c < 4; ++c) {
#pragma unroll
    for (int rr = 0; rr < 4; ++rr) {
      if (rr > c) {
        bool sw = fabsf(Nf[rr*4+c]) > fabsf(Nf[c*4+c]);
#pragma unroll
        for (int j = 0; j < 4; ++j) {
          float tn = Nf[c*4+j], tb = Bf[c*4+j];
          Nf[c*4+j]  = sw ? Nf[rr*4+j] : tn;
          Nf[rr*4+j] = sw ? tn         : Nf[rr*4+j];
          Bf[c*4+j]  = sw ? Bf[rr*4+j] : tb;
          Bf[rr*4+j] = sw ? tb         : Bf[rr*4+j];
        }
      }
    }
    float inv = 1.f / Nf[c*4+c];
#pragma unroll
    for (int j = 0; j < 4; ++j) { Nf[c*4+j] *= inv; Bf[c*4+j] *= inv; }
#pragma unroll
    for (int rr = 0; rr < 4; ++rr) {
      if (rr != c) {
        float fq = Nf[rr*4+c];
#pragma unroll
        for (int j = 0; j < 4; ++j) {
          Nf[rr*4+j] = fmaf(-fq, Nf[c*4+j], Nf[rr*4+j]);
          Bf[rr*4+j] = fmaf(-fq, Bf[c*4+j], Bf[rr*4+j]);
        }
      }
    }
  }

  v2f R[8];
#pragma unroll
  for (int ip = 0; ip < 8; ++ip) R[ip] = mkv2(Bf[2*ip], Bf[2*ip+1]);
  for (int k = 0; k < n; ++k) {   // divergent trip count is fine (exec-masked)
    v2f T[8];
    mm4v(T, R, R);
#pragma unroll
    for (int ip = 0; ip < 8; ++ip) R[ip] = T[ip];
  }

  // y = max(P,1e-30) @ f ; dy = Q @ y
#pragma unroll
  for (int i = 0; i < 4; ++i) {
    float p0 = fmaxf(R[2*i].x, 1e-30f),   p1 = fmaxf(R[2*i].y, 1e-30f);
    float p2 = fmaxf(R[2*i+1].x, 1e-30f), p3 = fmaxf(R[2*i+1].y, 1e-30f);
    y[i] = fmaf(p0, f[0], fmaf(p1, f[1], fmaf(p2, f[2], p3 * f[3])));
  }
#pragma unroll
  for (int i = 0; i < 4; ++i) {
    v2f acc = Qm[2*i] * mkv2(y[0], y[1]);
    acc = v2fma(Qm[2*i+1], mkv2(y[2], y[3]), acc);
    dy[i] = acc.x + acc.y;
  }
}

// Prologue: U0T[j][s] = b1[j] + sum_k sp[s,k]*W1[2+k,j]  (iteration/v-invariant MLP part)
__global__ __launch_bounds__(256) void u0_kernel(const float* __restrict__ spg,
                                                 const float* __restrict__ W1g,
                                                 const float* __restrict__ b1g,
                                                 float* __restrict__ U0T) {
  const int j = blockIdx.x;     // 0..63 (wave-uniform -> W1 via s_load)
  const int s = threadIdx.x;    // 0..255
  float acc = b1g[j];
#pragma unroll
  for (int k = 0; k < 16; ++k) acc = fmaf(spg[s*16 + k], W1g[(2 + k)*64 + j], acc);
  U0T[j*256 + s] = acc;
}

// block = one v (1024 blocks), thread = one site s (256 threads).
__global__ __launch_bounds__(256) void mlme_kernel(
    const float* __restrict__ c1g, const float* __restrict__ c2g,
    const float* __restrict__ lf1g, const float* __restrict__ lf2g,
    const float* __restrict__ W1g,
    const float* __restrict__ Wqg, const float* __restrict__ bqg,
    const float* __restrict__ Wpg, const float* __restrict__ bpg,
    const float* __restrict__ U0T,
    float* __restrict__ outg)
{
  __shared__ float sred[8];
  __shared__ float sAB[2];
  __shared__ float sPQ[8];

  const int v = blockIdx.x;
  const int tid = threadIdx.x;
  const int lane = tid & 63;
  const int wid = tid >> 6;

  if (tid == 0) {
    float c10 = c1g[2*v], c11 = c1g[2*v+1];
    float c20 = c2g[2*v], c21 = c2g[2*v+1];
    float pn = sqrtf(c10*c10 + c11*c11 + EPSf);
    float qn = sqrtf(c20*c20 + c21*c21 + EPSf);
    float p0 = c10, p1 = c11, q0 = c20, q1 = c21;
    if (pn > qn) { float rr = qn/pn; p0 = c10*rr; p1 = c11*rr; }
    if (qn > pn) { float rr = pn/qn; q0 = c20*rr; q1 = c21*rr; }
    sPQ[0]=p0; sPQ[1]=p1; sPQ[2]=q0; sPQ[3]=q1;
    sPQ[4]=c10; sPQ[5]=c11; sPQ[6]=c20; sPQ[7]=c21;
    sAB[0]=0.5f; sAB[1]=0.5f;
  }

  // f = exp(log_felsenstein) per thread, once
  float f1[4], f2[4];
  {
    float4 a = reinterpret_cast<const float4*>(lf1g)[v*256 + tid];
    float4 b = reinterpret_cast<const float4*>(lf2g)[v*256 + tid];
    f1[0]=__expf(a.x); f1[1]=__expf(a.y); f1[2]=__expf(a.z); f1[3]=__expf(a.w);
    f2[0]=__expf(b.x); f2[1]=__expf(b.y); f2[2]=__expf(b.z); f2[3]=__expf(b.w);
  }
  __syncthreads();

  const v2f* bq2 = reinterpret_cast<const v2f*>(bqg);
  const v2f* bp2 = reinterpret_cast<const v2f*>(bpg);
  const v2f* Wq2 = reinterpret_cast<const v2f*>(Wqg);
  const v2f* Wp2 = reinterpret_cast<const v2f*>(Wpg);

  for (int it = 0; it < 3; ++it) {
    const float alpha = sAB[0], beta = sAB[1];
    const float p0=sPQ[0], p1=sPQ[1], q0=sPQ[2], q1=sPQ[3];
    const float c10=sPQ[4], c11=sPQ[5], c20=sPQ[6], c21=sPQ[7];
    const float mid0 = p0*alpha + q0*(1.f-alpha);
    const float mid1 = p1*alpha + q1*(1.f-alpha);
    const float par0 = mid0*beta, par1 = mid1*beta;
    const float d10 = c10-par0, d11 = c11-par1;
    const float d20 = c20-par0, d21 = c21-par1;
    const float t1 = sqrtf(d10*d10 + d11*d11 + EPSf);
    const float t2 = sqrtf(d20*d20 + d21*d21 + EPSf);

    // MLP (site part precomputed in U0T)
    v2f q2[8], p2[2];
#pragma unroll
    for (int k = 0; k < 8; ++k) q2[k] = bq2[k];
    p2[0] = bp2[0]; p2[1] = bp2[1];
#pragma unroll 4
    for (int j = 0; j < 64; ++j) {
      float u = U0T[j*256 + tid];
      float h = fmaxf(fmaf(par1, W1g[64 + j], fmaf(par0, W1g[j], u)), 0.f);
      v2f hh = mkv2(h, h);
#pragma unroll
      for (int k = 0; k < 8; ++k) q2[k] = v2fma(hh, Wq2[j*8 + k], q2[k]);
      p2[0] = v2fma(hh, Wp2[j*2 + 0], p2[0]);
      p2[1] = v2fma(hh, Wp2[j*2 + 1], p2[1]);
    }
    float qraw[16];
#pragma unroll
    for (int k = 0; k < 8; ++k) { qraw[2*k] = q2[k].x; qraw[2*k+1] = q2[k].y; }
    float praw[4] = { p2[0].x, p2[0].y, p2[1].x, p2[1].y };

    // rate matrix (off-diag softplus, rows sum to 0)
    v2f Qm[8];
    float Qd[16];
#pragma unroll
    for (int a = 0; a < 4; ++a) {
      float rs = 0.f;
#pragma unroll
      for (int b = 0; b < 4; ++b) {
        if (b != a) {
          float xx = qraw[a*4+b];
          float r = fmaxf(xx, 0.f) + __logf(1.f + __expf(-fabsf(xx)));
          Qd[a*4+b] = r;
          rs += r;
        }
      }
      Qd[a*4+a] = -rs;
    }
#pragma unroll
    for (int ip = 0; ip < 8; ++ip) Qm[ip] = mkv2(Qd[2*ip], Qd[2*ip+1]);

    // unnormalized stationary probs (normalization cancels in the gradient ratio)
    float st[4];
    {
      float m = fmaxf(fmaxf(praw[0],praw[1]), fmaxf(praw[2],praw[3]));
      st[0]=__expf(praw[0]-m); st[1]=__expf(praw[1]-m);
      st[2]=__expf(praw[2]-m); st[3]=__expf(praw[3]-m);
    }

    // shared Q powers + 1-norm (L1(Q*t) = t * L1(Q), t>0)
    v2f Q2[8], Q4[8], Q6[8];
    mm4v(Q2, Qm, Qm);
    mm4v(Q4, Q2, Q2);
    mm4v(Q6, Q4, Q2);
    float L1Q;
    {
      float cs0 = fabsf(Qd[0]) + fabsf(Qd[4]) + fabsf(Qd[8])  + fabsf(Qd[12]);
      float cs1 = fabsf(Qd[1]) + fabsf(Qd[5]) + fabsf(Qd[9])  + fabsf(Qd[13]);
      float cs2 = fabsf(Qd[2]) + fabsf(Qd[6]) + fabsf(Qd[10]) + fabsf(Qd[14]);
      float cs3 = fabsf(Qd[3]) + fabsf(Qd[7]) + fabsf(Qd[11]) + fabsf(Qd[15]);
      L1Q = fmaxf(fmaxf(cs0, cs1), fmaxf(cs2, cs3));
    }

    float y1[4], dy1[4], y2[4], dy2[4];
    site_branch(Qm, Q2, Q4, Q6, L1Q, t1, f1, y1, dy1);
    site_branch(Qm, Q2, Q4, Q6, L1Q, t2, f2, y2, dy2);

    // g_k = sum_a (dy_k)_a * (other y)_a * st_a / sum_a y1_a y2_a st_a
    float den  = 0.f, num1 = 0.f, num2 = 0.f;
#pragma unroll
    for (int a = 0; a < 4; ++a) {
      float ys2 = y2[a] * st[a];
      den  = fmaf(y1[a],  ys2, den);
      num1 = fmaf(dy1[a], ys2, num1);
      num2 = fmaf(y1[a] * st[a], dy2[a], num2);
    }
    float invden = 1.f / den;
    float g1c = num1 * invden;
    float g2c = num2 * invden;

#pragma unroll
    for (int off = 32; off > 0; off >>= 1) {
      g1c += __shfl_xor(g1c, off, 64);
      g2c += __shfl_xor(g2c, off, 64);
    }
    if (lane == 0) { sred[wid*2+0] = g1c; sred[wid*2+1] = g2c; }
    __syncthreads();
    if (tid == 0) {
      float g1 = sred[0]+sred[2]+sred[4]+sred[6];
      float g2 = sred[1]+sred[3]+sred[5]+sred[7];
      float db1da = ((par0-c10)*(p0-q0) + (par1-c11)*(p1-q1)) * beta / t1;
      float db2da = ((par0-c20)*(p0-q0) + (par1-c21)*(p1-q1)) * beta / t2;
      float db1db = ((par0-c10)*mid0 + (par1-c11)*mid1) / t1;
      float db2db = ((par0-c20)*mid0 + (par1-c21)*mid1) / t2;
      float ga = g1*db1da + g2*db2da;
      float gb = g1*db1db + g2*db2db;
      ga = fminf(1.f, fmaxf(-1.f, ga));
      gb = fminf(1.f, fmaxf(-1.f, gb));
      sAB[0] = fminf(1.f, fmaxf(0.f, alpha + 0.1f*ga));
      sAB[1] = fminf(1.f, fmaxf(0.f, beta  + 0.1f*gb));
    }
    __syncthreads();
  }

  if (tid == 0) {
    const float alpha = sAB[0], beta = sAB[1];
    const float p0=sPQ[0], p1=sPQ[1], q0=sPQ[2], q1=sPQ[3];
    float mid0 = p0*alpha + q0*(1.f-alpha);
    float mid1 = p1*alpha + q1*(1.f-alpha);
    outg[2*v]   = mid0*beta;
    outg[2*v+1] = mid1*beta;
  }
}

extern "C" void kernel_launch(void* const* d_in, const int* in_sizes, int n_in,
                              void* d_out, int out_size, void* d_ws, size_t ws_size,
                              hipStream_t stream) {
  (void)in_sizes; (void)n_in; (void)ws_size; (void)out_size;
  const float* c1  = (const float*)d_in[0];
  const float* c2  = (const float*)d_in[1];
  const float* lf1 = (const float*)d_in[2];
  const float* lf2 = (const float*)d_in[3];
  const float* sp  = (const float*)d_in[4];
  const float* W1  = (const float*)d_in[5];
  const float* b1  = (const float*)d_in[6];
  const float* Wq  = (const float*)d_in[7];
  const float* bq  = (const float*)d_in[8];
  const float* Wp  = (const float*)d_in[9];
  const float* bp  = (const float*)d_in[10];
  float* out = (float*)d_out;
  float* U0T = (float*)d_ws;  // 64*256 floats = 64 KB

  u0_kernel<<<dim3(64), dim3(256), 0, stream>>>(sp, W1, b1, U0T);
  mlme_kernel<<<dim3(1024), dim3(256), 0, stream>>>(
      c1, c2, lf1, lf2, W1, Wq, bq, Wp, bp, U0T, out);
}